// Round 4
// baseline (2256.116 us; speedup 1.0000x reference)
//
#include <hip/hip_runtime.h>

#define NUSERS 100000
#define NITEMS 200000
#define NNODES 300000
#define DIM 64
#define NEDGES 9600000
#define SCAN_BLK 1024
#define NBLK1 ((NNODES + SCAN_BLK - 1) / SCAN_BLK)   // 293

static_assert(NBLK1 <= 512, "scan2 assumes block sums fit one 512-thread block");

// ---------------------------------------------------------------------------
// concat: e0 = [user_emb; item_emb], float4
// ---------------------------------------------------------------------------
__global__ void concat_kernel(const float4* __restrict__ u,
                              const float4* __restrict__ it,
                              float4* __restrict__ e0) {
    int i = blockIdx.x * blockDim.x + threadIdx.x;
    const int nu4  = NUSERS * (DIM / 4);
    const int tot4 = NNODES * (DIM / 4);
    if (i < tot4) e0[i] = (i < nu4) ? u[i] : it[i - nu4];
}

// ---------------------------------------------------------------------------
// CSR build: histogram -> scan -> scatter (packed int2 payload)
// ---------------------------------------------------------------------------
__global__ void hist_kernel(const int* __restrict__ row, int* __restrict__ cnt) {
    int e = blockIdx.x * blockDim.x + threadIdx.x;
    if (e < NEDGES) atomicAdd(&cnt[row[e]], 1);
}

__global__ void scan1_kernel(const int* __restrict__ cnt,
                             int* __restrict__ excl,
                             int* __restrict__ blockSums) {
    __shared__ int sm[SCAN_BLK];
    int t = threadIdx.x;
    int g = blockIdx.x * SCAN_BLK + t;
    int v = (g < NNODES) ? cnt[g] : 0;
    sm[t] = v;
    __syncthreads();
    for (int off = 1; off < SCAN_BLK; off <<= 1) {
        int tmp = (t >= off) ? sm[t - off] : 0;
        __syncthreads();
        sm[t] += tmp;
        __syncthreads();
    }
    if (g < NNODES) excl[g] = sm[t] - v;
    if (t == SCAN_BLK - 1) blockSums[blockIdx.x] = sm[t];
}

__global__ void scan2_kernel(int* __restrict__ blockSums) {
    __shared__ int sm[512];
    int t = threadIdx.x;
    sm[t] = (t < NBLK1) ? blockSums[t] : 0;
    __syncthreads();
    for (int off = 1; off < 512; off <<= 1) {
        int tmp = (t >= off) ? sm[t - off] : 0;
        __syncthreads();
        sm[t] += tmp;
        __syncthreads();
    }
    if (t < NBLK1) blockSums[t] = sm[t];
}

__global__ void scan3_kernel(int* __restrict__ ptr, int* __restrict__ cursor,
                             const int* __restrict__ blockIncl) {
    int b = blockIdx.x;
    int g = b * SCAN_BLK + threadIdx.x;
    int off = (b > 0) ? blockIncl[b - 1] : 0;
    if (g < NNODES) {
        int p = ptr[g] + off;
        ptr[g] = p;
        cursor[g] = p;
    }
    if (g == 0) { ptr[NNODES] = NEDGES; cursor[NNODES] = NEDGES; }
}

__global__ void scatter_kernel(const int* __restrict__ row,
                               const int* __restrict__ col,
                               const float* __restrict__ val,
                               int* __restrict__ cursor,
                               int2* __restrict__ csr) {
    int e = blockIdx.x * blockDim.x + threadIdx.x;
    if (e >= NEDGES) return;
    int pos = atomicAdd(&cursor[row[e]], 1);
    csr[pos] = make_int2(col[e], __float_as_int(val[e]));
}

// ---------------------------------------------------------------------------
// gather-only SpMM: 2 rows per wave, lane = float2 (32 lanes x 2 dims)
// ---------------------------------------------------------------------------
__global__ void spmm_csr_kernel(const int* __restrict__ ptr,
                                const int2* __restrict__ csr,
                                const float2* __restrict__ x,
                                float2* __restrict__ y) {
    int w     = (blockIdx.x * blockDim.x + threadIdx.x) >> 6;  // wave id
    int half  = (threadIdx.x >> 5) & 1;
    int lane  = threadIdx.x & 31;
    int r     = w * 2 + half;
    if (r >= NNODES) return;
    int beg = ptr[r], end = ptr[r + 1];
    float2 acc = {0.f, 0.f};
    int i = beg;
    for (; i + 4 <= end; i += 4) {
        int2 a = csr[i], b = csr[i + 1], c = csr[i + 2], d = csr[i + 3];
        float2 x0 = x[(size_t)a.x * 32 + lane];
        float2 x1 = x[(size_t)b.x * 32 + lane];
        float2 x2 = x[(size_t)c.x * 32 + lane];
        float2 x3 = x[(size_t)d.x * 32 + lane];
        float v0 = __int_as_float(a.y), v1 = __int_as_float(b.y);
        float v2 = __int_as_float(c.y), v3 = __int_as_float(d.y);
        acc.x += v0 * x0.x; acc.y += v0 * x0.y;
        acc.x += v1 * x1.x; acc.y += v1 * x1.y;
        acc.x += v2 * x2.x; acc.y += v2 * x2.y;
        acc.x += v3 * x3.x; acc.y += v3 * x3.y;
    }
    for (; i < end; ++i) {
        int2 a = csr[i];
        float2 x0 = x[(size_t)a.x * 32 + lane];
        float v0 = __int_as_float(a.y);
        acc.x += v0 * x0.x; acc.y += v0 * x0.y;
    }
    y[(size_t)r * 32 + lane] = acc;
}

// ---------------------------------------------------------------------------
// fallback atomic SpMM (only if ws_size too small)
// ---------------------------------------------------------------------------
__global__ void spmm_atomic_kernel(const int* __restrict__ row,
                                   const int* __restrict__ col,
                                   const float* __restrict__ val,
                                   const float* __restrict__ x,
                                   float* __restrict__ y) {
    long long tid = (long long)blockIdx.x * blockDim.x + threadIdx.x;
    if (tid >= (long long)NEDGES * 16) return;
    int e = (int)(tid >> 4);
    int q = (int)(tid & 15);
    int r = row[e], c = col[e];
    float v = val[e];
    float4 xv = ((const float4*)x)[(size_t)c * 16 + q];
    float* yp = y + (size_t)r * 64 + q * 4;
    atomicAdd(yp + 0, v * xv.x);
    atomicAdd(yp + 1, v * xv.y);
    atomicAdd(yp + 2, v * xv.z);
    atomicAdd(yp + 3, v * xv.w);
}

// ---------------------------------------------------------------------------
// finalize: mean over the 4 embeddings, split users/items
// ---------------------------------------------------------------------------
__global__ void finalize_kernel(const float4* __restrict__ e0,
                                const float4* __restrict__ e1,
                                const float4* __restrict__ e2,
                                const float4* __restrict__ e3,
                                float4* __restrict__ users,
                                float4* __restrict__ items) {
    int i = blockIdx.x * blockDim.x + threadIdx.x;
    const int tot4 = NNODES * (DIM / 4);
    if (i >= tot4) return;
    float4 a = e0[i], b = e1[i], c = e2[i], d = e3[i];
    float4 m;
    m.x = (a.x + b.x + c.x + d.x) * 0.25f;
    m.y = (a.y + b.y + c.y + d.y) * 0.25f;
    m.z = (a.z + b.z + c.z + d.z) * 0.25f;
    m.w = (a.w + b.w + c.w + d.w) * 0.25f;
    const int nu4 = NUSERS * (DIM / 4);
    if (i < nu4) users[i] = m;
    else         items[i - nu4] = m;
}

extern "C" void kernel_launch(void* const* d_in, const int* in_sizes, int n_in,
                              void* d_out, int out_size, void* d_ws, size_t ws_size,
                              hipStream_t stream) {
    const float* user_emb = (const float*)d_in[0];
    const float* item_emb = (const float*)d_in[1];
    const int*   adj_row  = (const int*)d_in[2];
    const int*   adj_col  = (const int*)d_in[3];
    const float* adj_val  = (const float*)d_in[4];

    float* out   = (float*)d_out;
    float* users = out;
    float* items = out + (size_t)NUSERS * DIM;
    float* e0    = out + (size_t)NNODES * DIM;
    float* e1    = e0 + (size_t)NNODES * DIM;
    float* e2    = e1 + (size_t)NNODES * DIM;
    float* e3    = e2 + (size_t)NNODES * DIM;

    const int tot4 = NNODES * (DIM / 4);
    const int cblk = 256;
    const int cgrid = (tot4 + cblk - 1) / cblk;

    concat_kernel<<<cgrid, cblk, 0, stream>>>(
        (const float4*)user_emb, (const float4*)item_emb, (float4*)e0);

    // workspace layout
    char* ws = (char*)d_ws;
    size_t off = 0;
    auto alloc = [&](size_t bytes) { char* p = ws + off; off += (bytes + 255) & ~(size_t)255; return p; };
    int*  ptr       = (int*) alloc((NNODES + 1) * sizeof(int));
    int*  cursor    = (int*) alloc((NNODES + 1) * sizeof(int));
    int*  blockSums = (int*) alloc(512 * sizeof(int));
    int2* csr       = (int2*)alloc((size_t)NEDGES * sizeof(int2));
    bool have_ws = (off <= ws_size);

    const int eblk = 256;
    const int egrid = (NEDGES + eblk - 1) / eblk;

    if (have_ws) {
        hipMemsetAsync(cursor, 0, (NNODES + 1) * sizeof(int), stream);
        hist_kernel<<<egrid, eblk, 0, stream>>>(adj_row, cursor);
        scan1_kernel<<<NBLK1, SCAN_BLK, 0, stream>>>(cursor, ptr, blockSums);
        scan2_kernel<<<1, 512, 0, stream>>>(blockSums);
        scan3_kernel<<<NBLK1, SCAN_BLK, 0, stream>>>(ptr, cursor, blockSums);
        scatter_kernel<<<egrid, eblk, 0, stream>>>(adj_row, adj_col, adj_val,
                                                   cursor, csr);

        // gather-only SpMM: 2 rows per wave
        const int sblk = 256;                         // 4 waves = 8 rows/block
        const int sgrid = (NNODES / 2 + 3) / 4;       // 37500 blocks
        spmm_csr_kernel<<<sgrid, sblk, 0, stream>>>(ptr, csr, (const float2*)e0, (float2*)e1);
        spmm_csr_kernel<<<sgrid, sblk, 0, stream>>>(ptr, csr, (const float2*)e1, (float2*)e2);
        spmm_csr_kernel<<<sgrid, sblk, 0, stream>>>(ptr, csr, (const float2*)e2, (float2*)e3);
    } else {
        hipMemsetAsync(e1, 0, (size_t)3 * NNODES * DIM * sizeof(float), stream);
        const long long st = (long long)NEDGES * 16;
        const int sgrid = (int)((st + 255) / 256);
        spmm_atomic_kernel<<<sgrid, 256, 0, stream>>>(adj_row, adj_col, adj_val, e0, e1);
        spmm_atomic_kernel<<<sgrid, 256, 0, stream>>>(adj_row, adj_col, adj_val, e1, e2);
        spmm_atomic_kernel<<<sgrid, 256, 0, stream>>>(adj_row, adj_col, adj_val, e2, e3);
    }

    finalize_kernel<<<cgrid, cblk, 0, stream>>>(
        (const float4*)e0, (const float4*)e1, (const float4*)e2, (const float4*)e3,
        (float4*)users, (float4*)items);
}